// Round 17
// baseline (409.153 us; speedup 1.0000x reference)
//
#include <hip/hip_runtime.h>
#include <hip/hip_bf16.h>
#include <stdint.h>

// ---------------------------------------------------------------------------
// LSTM cell, fused as one bf16 MFMA GEMM:
//   A  = [input | hidden]            : [16384][2048]  (bf16, packed in ws)
//   W  = [Wx[g] | Wh[g]] per gate g  : [4096][2048]   (bf16, packed in ws, [N][K])
//   pre[g][b][s] = sum_k A[b][k] * W[g*1024+s][k] + bias[g][s]
//
// Round 17 = r16 champion (GEMM 277us / 995 TF, total 311.5us) MINUS the
// s_setprio pair (single variable). T5 evidence (m190): setprio on a
// lockstep barrier-synced GEMM (our structure -- no wave role-split) is
// null-to-negative (-14 TF within-probe); it also competes against the
// co-resident block's DMA-issue waves. Removing is the last zero-risk
// evidence-backed lever.
//
// Champion structure (validated over r6-r16):
//   * block 128r x 64s x 4 gates, BK=64, 48KB single-buffer LDS -> 2 blk/CU
//     (measured threshold: 48KB -> 2 blk/CU, >=64KB -> 1 blk/CU)
//   * 8 waves 2Mx4N, wave = 64r x 16s x 4g, acc[4][4] f32x4 (0.5 reads/MFMA)
//   * global_load_lds DMA staging (NO staging registers -- reg-staging spills
//     at this occupancy: r3-r5's 2.9GB scratch-write lesson)
//   * verified XOR swizzle: pre-swizzled global col, read slot ^ (lr&7)<<3;
//     SQ_LDS_BANK_CONFLICT == 0
//   * explicit vmcnt(0) before __syncthreads (replay-safety, r1 lesson)
//   * XCD remap row-stripe-major (FETCH 340MB vs col-major 589MB, r12/r16)
//   * fused sigmoid/tanh/cell epilogue; merged single pack dispatch
// ---------------------------------------------------------------------------

typedef short bf16x8 __attribute__((ext_vector_type(8)));
typedef float f32x4 __attribute__((ext_vector_type(4)));

#define B_ROWS 16384
#define D_K 2048

__device__ __forceinline__ unsigned short f2bf(float f) {
    unsigned u = __builtin_bit_cast(unsigned, f);
    u += 0x7FFFu + ((u >> 16) & 1u);   // round-to-nearest-even
    return (unsigned short)(u >> 16);
}

__device__ __forceinline__ float sigf(float x) { return 1.0f / (1.0f + __expf(-x)); }
__device__ __forceinline__ float tanhfast(float x) { return 2.0f / (1.0f + __expf(-2.0f * x)) - 1.0f; }

// global -> LDS direct copy, 16B per lane; LDS dest wave-uniform base + lane*16.
#define GLD16(gp, lp)                                                          \
    __builtin_amdgcn_global_load_lds(                                          \
        (const __attribute__((address_space(1))) unsigned int*)(gp),           \
        (__attribute__((address_space(3))) unsigned int*)(lp), 16, 0, 0)

// --------------------------- merged pack kernel ----------------------------

__global__ void pack_all_kernel(const float* __restrict__ x,
                                const float* __restrict__ h,
                                const float* __restrict__ Wx,
                                const float* __restrict__ Wh,
                                const float* __restrict__ bx,
                                const float* __restrict__ bh,
                                unsigned short* __restrict__ A,
                                unsigned short* __restrict__ W,
                                float* __restrict__ bias) {
    const int totalA = B_ROWS * (D_K / 4);         // 8,388,608
    const int totalW = 4096 * (D_K / 4);           // 2,097,152
    const int total = totalA + totalW + 4096;
    for (int v = blockIdx.x * blockDim.x + threadIdx.x; v < total;
         v += gridDim.x * blockDim.x) {
        if (v < totalA) {
            const int b = v >> 9;
            const int k0 = (v & 511) << 2;
            const float* src = (k0 < 1024) ? (x + (size_t)b * 1024 + k0)
                                           : (h + (size_t)b * 1024 + (k0 - 1024));
            float4 f = *(const float4*)src;
            unsigned p0 = (unsigned)f2bf(f.x) | ((unsigned)f2bf(f.y) << 16);
            unsigned p1 = (unsigned)f2bf(f.z) | ((unsigned)f2bf(f.w) << 16);
            uint2 o; o.x = p0; o.y = p1;
            *(uint2*)(A + (size_t)v * 4) = o;
        } else if (v < totalA + totalW) {
            const int u = v - totalA;
            const int n = u >> 9;                  // n = g*1024 + s
            const int k0 = (u & 511) << 2;
            const float* src = (k0 < 1024) ? (Wx + (size_t)n * 1024 + k0)
                                           : (Wh + (size_t)n * 1024 + (k0 - 1024));
            float4 f = *(const float4*)src;
            unsigned p0 = (unsigned)f2bf(f.x) | ((unsigned)f2bf(f.y) << 16);
            unsigned p1 = (unsigned)f2bf(f.z) | ((unsigned)f2bf(f.w) << 16);
            uint2 o; o.x = p0; o.y = p1;
            *(uint2*)(W + (size_t)u * 4) = o;
        } else {
            const int i = v - totalA - totalW;
            bias[i] = bx[i] + bh[i];
        }
    }
}

// --------------------------- fused GEMM ------------------------------------
// Tile: BM=128 rows (b), BN=64 cols (s) x 4 gates, BK=64.
// 512 threads = 8 waves 2M x 4N: wave = 64r x 16s x 4g -> acc[4][4] f32x4.

__global__ __launch_bounds__(512, 2) void lstm_gemm_kernel(
    const unsigned short* __restrict__ A,     // [16384][2048]
    const unsigned short* __restrict__ W,     // [4096][2048]
    const float* __restrict__ bias,           // [4096]
    const float* __restrict__ cell,           // [16384][1024]
    float* __restrict__ out) {                // new_c then h, each [16384][1024]
    // 48 chunks of 1KB; chunk c holds 8 rows x 64 elems (A: 0..15, W: 16..47)
    __shared__ __align__(16) unsigned short smem[24576];

    // XCD-aware remap: 2048 blocks, 8 XCDs, 256 blocks/XCD (bijective).
    const int bid = blockIdx.x;
    const int wg = (bid & 7) * 256 + (bid >> 3);
    const int brow = (wg >> 4) << 7;          // row stripe * 128
    const int bcol = (wg & 15) << 6;          // col tile * 64

    const int tid = threadIdx.x;
    const int wid = tid >> 6;                 // 0..7
    const int lane = tid & 63;
    const int wr = wid >> 2;                  // 0..1: rows wr*64..+64
    const int wc = wid & 3;                   // 0..3: s-cols wc*16..+16
    const int lr = lane & 15, lg = lane >> 4;
    const int l8 = lane >> 3;                 // row within a 1KB staging chunk
    // PRE-SWIZZLED global column (verified: 0 conflicts): linear LDS slot
    // (lane&7) receives global col ((lane&7)^l8)*8.
    const int lcol = (((lane & 7) ^ l8) << 3);

    f32x4 acc[4][4];
#pragma unroll
    for (int g = 0; g < 4; ++g)
#pragma unroll
        for (int m = 0; m < 4; ++m) acc[g][m] = (f32x4){0.f, 0.f, 0.f, 0.f};

    // staging sources: wave w owns chunks w*6..w*6+5 (per-lane addresses)
    const unsigned short* gp[6];
#pragma unroll
    for (int i = 0; i < 6; ++i) {
        const int c = wid * 6 + i;
        if (c < 16) {
            gp[i] = A + (size_t)(brow + c * 8 + l8) * D_K + lcol;
        } else {
            const int cw = c - 16;
            gp[i] = W + (size_t)((cw >> 3) * 1024 + bcol + (cw & 7) * 8 + l8) * D_K + lcol;
        }
    }

    for (int kt = 0; kt < D_K; kt += 64) {
        // direct global->LDS DMA, no staging registers
#pragma unroll
        for (int i = 0; i < 6; ++i)
            GLD16(gp[i] + kt, (char*)smem + (wid * 6 + i) * 1024);
        asm volatile("s_waitcnt vmcnt(0)" ::: "memory");
        __syncthreads();

#pragma unroll
        for (int kk = 0; kk < 2; ++kk) {
            // swizzled k-column (elems); fragment row&7 == lr&7 everywhere
            const int swk = (kk * 32 + lg * 8) ^ ((lr & 7) << 3);
            bf16x8 a[4], w[4];
#pragma unroll
            for (int m = 0; m < 4; ++m)
                a[m] = *(const bf16x8*)&smem[(wr * 64 + m * 16 + lr) * 64 + swk];
#pragma unroll
            for (int g = 0; g < 4; ++g)
                w[g] = *(const bf16x8*)&smem[8192 + (g * 64 + wc * 16 + lr) * 64 + swk];
#pragma unroll
            for (int g = 0; g < 4; ++g) {
#pragma unroll
                for (int m = 0; m < 4; ++m)
                    acc[g][m] = __builtin_amdgcn_mfma_f32_16x16x32_bf16(
                        a[m], w[g], acc[g][m], 0, 0, 0);
            }
        }
        __syncthreads();
    }

    // fused epilogue: C/D layout col = lane&15, row = (lane>>4)*4 + reg
    float bv[4];
#pragma unroll
    for (int g = 0; g < 4; ++g) bv[g] = bias[(g << 10) + bcol + wc * 16 + lr];

    float* outc = out;
    float* outh = out + (size_t)B_ROWS * 1024;
#pragma unroll
    for (int m = 0; m < 4; ++m) {
#pragma unroll
        for (int r = 0; r < 4; ++r) {
            const int b = brow + wr * 64 + m * 16 + lg * 4 + r;
            const size_t idx = (size_t)b * 1024 + bcol + wc * 16 + lr;
            float pf = acc[0][m][r] + bv[0];
            float pi = acc[1][m][r] + bv[1];
            float pc = acc[2][m][r] + bv[2];
            float po = acc[3][m][r] + bv[3];
            float cl = cell[idx];
            float nc = cl * sigf(pf) + sigf(pi) * tanhfast(pc);
            outc[idx] = nc;
            outh[idx] = tanhfast(nc) * sigf(po);
        }
    }
}

// ------------------- fp32 fallback (ws too small; slow but correct) --------

__global__ void lstm_naive_kernel(const float* __restrict__ x,
                                  const float* __restrict__ cell,
                                  const float* __restrict__ h,
                                  const float* __restrict__ Wx,
                                  const float* __restrict__ bx,
                                  const float* __restrict__ Wh,
                                  const float* __restrict__ bh,
                                  float* __restrict__ out) {
    int idx = blockIdx.x * blockDim.x + threadIdx.x;
    if (idx >= B_ROWS * 1024) return;
    int b = idx >> 10, s = idx & 1023;
    const float* xr = x + (size_t)b * 1024;
    const float* hr = h + (size_t)b * 1024;
    float pre[4];
#pragma unroll
    for (int g = 0; g < 4; ++g) {
        float acc = bx[(g << 10) + s] + bh[(g << 10) + s];
        const float* wx = Wx + ((size_t)(g << 10) + s) * 1024;
        const float* wh = Wh + ((size_t)(g << 10) + s) * 1024;
        for (int k = 0; k < 1024; ++k) acc += xr[k] * wx[k] + hr[k] * wh[k];
        pre[g] = acc;
    }
    float nc = cell[idx] * sigf(pre[0]) + sigf(pre[1]) * tanhfast(pre[2]);
    out[idx] = nc;
    out[(size_t)B_ROWS * 1024 + idx] = tanhfast(nc) * sigf(pre[3]);
}

// ---------------------------------------------------------------------------

extern "C" void kernel_launch(void* const* d_in, const int* in_sizes, int n_in,
                              void* d_out, int out_size, void* d_ws, size_t ws_size,
                              hipStream_t stream) {
    const float* x    = (const float*)d_in[0];
    const float* cell = (const float*)d_in[1];
    const float* hid  = (const float*)d_in[2];
    const float* Wx   = (const float*)d_in[3];
    const float* bx   = (const float*)d_in[4];
    const float* Wh   = (const float*)d_in[5];
    const float* bh   = (const float*)d_in[6];
    float* out = (float*)d_out;

    const size_t szA = (size_t)B_ROWS * D_K * 2;    // 64 MB
    const size_t szW = (size_t)4096 * D_K * 2;      // 16 MB
    const size_t szB = 4096 * 4;
    if (ws_size < szA + szW + szB) {
        lstm_naive_kernel<<<(B_ROWS * 1024) / 256, 256, 0, stream>>>(
            x, cell, hid, Wx, bx, Wh, bh, out);
        return;
    }

    unsigned short* Ab = (unsigned short*)d_ws;
    unsigned short* Wb = (unsigned short*)((char*)d_ws + szA);
    float* bias = (float*)((char*)d_ws + szA + szW);

    pack_all_kernel<<<8192, 256, 0, stream>>>(x, hid, Wx, Wh, bx, bh,
                                              Ab, Wb, bias);

    lstm_gemm_kernel<<<2048, 512, 0, stream>>>(Ab, Wb, bias, cell, out);
}

// Round 18
// 309.834 us; speedup vs baseline: 1.3206x; 1.3206x over previous
//
#include <hip/hip_runtime.h>
#include <hip/hip_bf16.h>
#include <stdint.h>

// ---------------------------------------------------------------------------
// LSTM cell, fused as one bf16 MFMA GEMM:
//   A  = [input | hidden]            : [16384][2048]  (bf16, packed in ws)
//   W  = [Wx[g] | Wh[g]] per gate g  : [4096][2048]   (bf16, packed in ws, [N][K])
//   pre[g][b][s] = sum_k A[b][k] * W[g*1024+s][k] + bias[g][s]
//
// Round 18 = r16 champion restored (GEMM 277us / 995 TF) + launch_bounds
// (512,2) -> (512,4) to make the 128-total-reg cap STRUCTURAL.
//
// r17 lesson (setprio removal -> 434us): occupancy halved because the
// allocator drifted 64 -> 68 arch VGPR; 68 + 64 AGPR = 132 > 128 crossed
// the waves/CU threshold (m69) -> 1 block/CU, TLP gone. The setprio pair
// had been accidentally pinning the allocator at 64. (512,4) contractually
// demands 4 waves/SIMD = 2 blocks/CU => <=128 total regs, so residency no
// longer depends on allocator luck. r10 precedent: same acc/epilogue
// compiled at (512,4) with 64 VGPR, zero spill.
//
// Champion structure (validated r6-r17):
//   * block 128r x 64s x 4 gates, BK=64, 48KB single-buffer LDS -> 2 blk/CU
//   * 8 waves 2Mx4N, wave = 64r x 16s x 4g, acc[4][4] f32x4 (0.5 reads/MFMA)
//   * global_load_lds DMA staging (reg-staging spills: r3-r5, 2.9GB scratch)
//   * verified XOR swizzle (0 conflicts), vmcnt(0)+syncthreads (replay-safe)
//   * XCD remap row-stripe-major (FETCH 340MB vs 589 col-major)
//   * s_setprio(1/0) around MFMA cluster (load-bearing, r17)
//   * fused sigmoid/tanh/cell epilogue; merged single pack dispatch
// ---------------------------------------------------------------------------

typedef short bf16x8 __attribute__((ext_vector_type(8)));
typedef float f32x4 __attribute__((ext_vector_type(4)));

#define B_ROWS 16384
#define D_K 2048

__device__ __forceinline__ unsigned short f2bf(float f) {
    unsigned u = __builtin_bit_cast(unsigned, f);
    u += 0x7FFFu + ((u >> 16) & 1u);   // round-to-nearest-even
    return (unsigned short)(u >> 16);
}

__device__ __forceinline__ float sigf(float x) { return 1.0f / (1.0f + __expf(-x)); }
__device__ __forceinline__ float tanhfast(float x) { return 2.0f / (1.0f + __expf(-2.0f * x)) - 1.0f; }

// global -> LDS direct copy, 16B per lane; LDS dest wave-uniform base + lane*16.
#define GLD16(gp, lp)                                                          \
    __builtin_amdgcn_global_load_lds(                                          \
        (const __attribute__((address_space(1))) unsigned int*)(gp),           \
        (__attribute__((address_space(3))) unsigned int*)(lp), 16, 0, 0)

// --------------------------- merged pack kernel ----------------------------

__global__ void pack_all_kernel(const float* __restrict__ x,
                                const float* __restrict__ h,
                                const float* __restrict__ Wx,
                                const float* __restrict__ Wh,
                                const float* __restrict__ bx,
                                const float* __restrict__ bh,
                                unsigned short* __restrict__ A,
                                unsigned short* __restrict__ W,
                                float* __restrict__ bias) {
    const int totalA = B_ROWS * (D_K / 4);         // 8,388,608
    const int totalW = 4096 * (D_K / 4);           // 2,097,152
    const int total = totalA + totalW + 4096;
    for (int v = blockIdx.x * blockDim.x + threadIdx.x; v < total;
         v += gridDim.x * blockDim.x) {
        if (v < totalA) {
            const int b = v >> 9;
            const int k0 = (v & 511) << 2;
            const float* src = (k0 < 1024) ? (x + (size_t)b * 1024 + k0)
                                           : (h + (size_t)b * 1024 + (k0 - 1024));
            float4 f = *(const float4*)src;
            unsigned p0 = (unsigned)f2bf(f.x) | ((unsigned)f2bf(f.y) << 16);
            unsigned p1 = (unsigned)f2bf(f.z) | ((unsigned)f2bf(f.w) << 16);
            uint2 o; o.x = p0; o.y = p1;
            *(uint2*)(A + (size_t)v * 4) = o;
        } else if (v < totalA + totalW) {
            const int u = v - totalA;
            const int n = u >> 9;                  // n = g*1024 + s
            const int k0 = (u & 511) << 2;
            const float* src = (k0 < 1024) ? (Wx + (size_t)n * 1024 + k0)
                                           : (Wh + (size_t)n * 1024 + (k0 - 1024));
            float4 f = *(const float4*)src;
            unsigned p0 = (unsigned)f2bf(f.x) | ((unsigned)f2bf(f.y) << 16);
            unsigned p1 = (unsigned)f2bf(f.z) | ((unsigned)f2bf(f.w) << 16);
            uint2 o; o.x = p0; o.y = p1;
            *(uint2*)(W + (size_t)u * 4) = o;
        } else {
            const int i = v - totalA - totalW;
            bias[i] = bx[i] + bh[i];
        }
    }
}

// --------------------------- fused GEMM ------------------------------------
// Tile: BM=128 rows (b), BN=64 cols (s) x 4 gates, BK=64.
// 512 threads = 8 waves 2M x 4N: wave = 64r x 16s x 4g -> acc[4][4] f32x4.

__global__ __launch_bounds__(512, 4) void lstm_gemm_kernel(
    const unsigned short* __restrict__ A,     // [16384][2048]
    const unsigned short* __restrict__ W,     // [4096][2048]
    const float* __restrict__ bias,           // [4096]
    const float* __restrict__ cell,           // [16384][1024]
    float* __restrict__ out) {                // new_c then h, each [16384][1024]
    // 48 chunks of 1KB; chunk c holds 8 rows x 64 elems (A: 0..15, W: 16..47)
    __shared__ __align__(16) unsigned short smem[24576];

    // XCD-aware remap: 2048 blocks, 8 XCDs, 256 blocks/XCD (bijective).
    const int bid = blockIdx.x;
    const int wg = (bid & 7) * 256 + (bid >> 3);
    const int brow = (wg >> 4) << 7;          // row stripe * 128
    const int bcol = (wg & 15) << 6;          // col tile * 64

    const int tid = threadIdx.x;
    const int wid = tid >> 6;                 // 0..7
    const int lane = tid & 63;
    const int wr = wid >> 2;                  // 0..1: rows wr*64..+64
    const int wc = wid & 3;                   // 0..3: s-cols wc*16..+16
    const int lr = lane & 15, lg = lane >> 4;
    const int l8 = lane >> 3;                 // row within a 1KB staging chunk
    // PRE-SWIZZLED global column (verified: 0 conflicts): linear LDS slot
    // (lane&7) receives global col ((lane&7)^l8)*8.
    const int lcol = (((lane & 7) ^ l8) << 3);

    f32x4 acc[4][4];
#pragma unroll
    for (int g = 0; g < 4; ++g)
#pragma unroll
        for (int m = 0; m < 4; ++m) acc[g][m] = (f32x4){0.f, 0.f, 0.f, 0.f};

    // staging sources: wave w owns chunks w*6..w*6+5 (per-lane addresses)
    const unsigned short* gp[6];
#pragma unroll
    for (int i = 0; i < 6; ++i) {
        const int c = wid * 6 + i;
        if (c < 16) {
            gp[i] = A + (size_t)(brow + c * 8 + l8) * D_K + lcol;
        } else {
            const int cw = c - 16;
            gp[i] = W + (size_t)((cw >> 3) * 1024 + bcol + (cw & 7) * 8 + l8) * D_K + lcol;
        }
    }

    for (int kt = 0; kt < D_K; kt += 64) {
        // direct global->LDS DMA, no staging registers
#pragma unroll
        for (int i = 0; i < 6; ++i)
            GLD16(gp[i] + kt, (char*)smem + (wid * 6 + i) * 1024);
        asm volatile("s_waitcnt vmcnt(0)" ::: "memory");
        __syncthreads();

#pragma unroll
        for (int kk = 0; kk < 2; ++kk) {
            // swizzled k-column (elems); fragment row&7 == lr&7 everywhere
            const int swk = (kk * 32 + lg * 8) ^ ((lr & 7) << 3);
            bf16x8 a[4], w[4];
#pragma unroll
            for (int m = 0; m < 4; ++m)
                a[m] = *(const bf16x8*)&smem[(wr * 64 + m * 16 + lr) * 64 + swk];
#pragma unroll
            for (int g = 0; g < 4; ++g)
                w[g] = *(const bf16x8*)&smem[8192 + (g * 64 + wc * 16 + lr) * 64 + swk];
            __builtin_amdgcn_s_setprio(1);
#pragma unroll
            for (int g = 0; g < 4; ++g) {
#pragma unroll
                for (int m = 0; m < 4; ++m)
                    acc[g][m] = __builtin_amdgcn_mfma_f32_16x16x32_bf16(
                        a[m], w[g], acc[g][m], 0, 0, 0);
            }
            __builtin_amdgcn_s_setprio(0);
        }
        __syncthreads();
    }

    // fused epilogue: C/D layout col = lane&15, row = (lane>>4)*4 + reg
    float bv[4];
#pragma unroll
    for (int g = 0; g < 4; ++g) bv[g] = bias[(g << 10) + bcol + wc * 16 + lr];

    float* outc = out;
    float* outh = out + (size_t)B_ROWS * 1024;
#pragma unroll
    for (int m = 0; m < 4; ++m) {
#pragma unroll
        for (int r = 0; r < 4; ++r) {
            const int b = brow + wr * 64 + m * 16 + lg * 4 + r;
            const size_t idx = (size_t)b * 1024 + bcol + wc * 16 + lr;
            float pf = acc[0][m][r] + bv[0];
            float pi = acc[1][m][r] + bv[1];
            float pc = acc[2][m][r] + bv[2];
            float po = acc[3][m][r] + bv[3];
            float cl = cell[idx];
            float nc = cl * sigf(pf) + sigf(pi) * tanhfast(pc);
            outc[idx] = nc;
            outh[idx] = tanhfast(nc) * sigf(po);
        }
    }
}

// ------------------- fp32 fallback (ws too small; slow but correct) --------

__global__ void lstm_naive_kernel(const float* __restrict__ x,
                                  const float* __restrict__ cell,
                                  const float* __restrict__ h,
                                  const float* __restrict__ Wx,
                                  const float* __restrict__ bx,
                                  const float* __restrict__ Wh,
                                  const float* __restrict__ bh,
                                  float* __restrict__ out) {
    int idx = blockIdx.x * blockDim.x + threadIdx.x;
    if (idx >= B_ROWS * 1024) return;
    int b = idx >> 10, s = idx & 1023;
    const float* xr = x + (size_t)b * 1024;
    const float* hr = h + (size_t)b * 1024;
    float pre[4];
#pragma unroll
    for (int g = 0; g < 4; ++g) {
        float acc = bx[(g << 10) + s] + bh[(g << 10) + s];
        const float* wx = Wx + ((size_t)(g << 10) + s) * 1024;
        const float* wh = Wh + ((size_t)(g << 10) + s) * 1024;
        for (int k = 0; k < 1024; ++k) acc += xr[k] * wx[k] + hr[k] * wh[k];
        pre[g] = acc;
    }
    float nc = cell[idx] * sigf(pre[0]) + sigf(pre[1]) * tanhfast(pre[2]);
    out[idx] = nc;
    out[(size_t)B_ROWS * 1024 + idx] = tanhfast(nc) * sigf(pre[3]);
}

// ---------------------------------------------------------------------------

extern "C" void kernel_launch(void* const* d_in, const int* in_sizes, int n_in,
                              void* d_out, int out_size, void* d_ws, size_t ws_size,
                              hipStream_t stream) {
    const float* x    = (const float*)d_in[0];
    const float* cell = (const float*)d_in[1];
    const float* hid  = (const float*)d_in[2];
    const float* Wx   = (const float*)d_in[3];
    const float* bx   = (const float*)d_in[4];
    const float* Wh   = (const float*)d_in[5];
    const float* bh   = (const float*)d_in[6];
    float* out = (float*)d_out;

    const size_t szA = (size_t)B_ROWS * D_K * 2;    // 64 MB
    const size_t szW = (size_t)4096 * D_K * 2;      // 16 MB
    const size_t szB = 4096 * 4;
    if (ws_size < szA + szW + szB) {
        lstm_naive_kernel<<<(B_ROWS * 1024) / 256, 256, 0, stream>>>(
            x, cell, hid, Wx, bx, Wh, bh, out);
        return;
    }

    unsigned short* Ab = (unsigned short*)d_ws;
    unsigned short* Wb = (unsigned short*)((char*)d_ws + szA);
    float* bias = (float*)((char*)d_ws + szA + szW);

    pack_all_kernel<<<8192, 256, 0, stream>>>(x, hid, Wx, Wh, bx, bh,
                                              Ab, Wb, bias);

    lstm_gemm_kernel<<<2048, 512, 0, stream>>>(Ab, Wb, bias, cell, out);
}